// Round 10
// baseline (314.628 us; speedup 1.0000x reference)
//
#include <hip/hip_runtime.h>
#include <hip/hip_bf16.h>

// Problem constants (match reference)
constexpr int cN = 50000;
constexpr int cE = 800000;
constexpr int cNUM_CLASSES = 40;
constexpr int cFEAT_DIM = 256;
constexpr int cFEAT_HID = 64;
constexpr int cDEG_HID = 32;
constexpr int cHID = 128;
constexpr int cMAX_DEG = 256;
constexpr int cKF = 352;                // fused conv1 K: 40 logits + 256 feat + 32 deg + 24 pad
constexpr int cAST1 = 360;              // conv1 LDS A stride (pad +8)

// LDS-histogram CSR build parameters
constexpr int cNCHUNK = 64;             // edge chunks (= copies per histogram)
constexpr int cCHUNK  = cE / cNCHUNK;   // 12500 edges per chunk (exact)
constexpr int cWORDS  = cN / 2;         // 25000 packed u16-pair words per histogram
constexpr int cHWORDS = cWORDS / 2;     // 12500 words per node-range half (50 KB LDS)
constexpr int cSCANB  = (cWORDS + 255) / 256; // 98 blocks for mega_scan

typedef unsigned short ushort8_t __attribute__((ext_vector_type(8)));
typedef short short8_t __attribute__((ext_vector_type(8)));
typedef float float4_t __attribute__((ext_vector_type(4)));

__device__ __forceinline__ unsigned short f2bf(float f) {
    unsigned u = __builtin_bit_cast(unsigned, f);
    u += 0x7fff + ((u >> 16) & 1); // RNE
    return (unsigned short)(u >> 16);
}
__device__ __forceinline__ float bf2f(unsigned short s) {
    unsigned u = ((unsigned)s) << 16;
    return __builtin_bit_cast(float, u);
}

// ---------------- prep: histograms + all weight preprocessing + desc init (R5-proven) ----------------
__global__ __launch_bounds__(256) void prep_kernel(const int* __restrict__ edge,
                                                   unsigned* __restrict__ partial,
                                                   const float* __restrict__ Wf,
                                                   const float* __restrict__ bfv,
                                                   const float* __restrict__ W1,
                                                   const float* __restrict__ W2,
                                                   const float* __restrict__ W3,
                                                   unsigned short* __restrict__ Btc,
                                                   unsigned short* __restrict__ Wt2,
                                                   unsigned short* __restrict__ Wt3,
                                                   float* __restrict__ bias2,
                                                   int* __restrict__ desc) {
    __shared__ unsigned lds[cHWORDS];
    const int b = blockIdx.x, tid = threadIdx.x;
    if (b < 256) {
        const int cb = b & (cNCHUNK - 1);
        const int half = (b >> 6) & 1;
        const int which = b >> 7;
        for (int i = tid; i < cHWORDS; i += 256) lds[i] = 0;
        __syncthreads();
        const int* ids = edge + (size_t)which * cE + (size_t)cb * cCHUNK;
        const int lo = half * (cN / 2), hi = lo + cN / 2;
        const int wbase = half * cHWORDS;
        for (int i = tid; i < cCHUNK; i += 256) {
            int v = ids[i];
            if (v >= lo && v < hi)
                atomicAdd(&lds[(v >> 1) - wbase], 1u << ((v & 1) * 16));
        }
        __syncthreads();
        unsigned* outp = partial + ((size_t)which * cNCHUNK + cb) * cWORDS + wbase;
        for (int i = tid; i < cHWORDS; i += 256) outp[i] = lds[i];
        return;
    }
    if (b < 392) {
        int i = (b - 256) * 256 + tid;
        if (i < 12288) {            // Btc: logits rows, deg rows, zero pad
            int n = i / 96, r = i - (i / 96) * 96;
            unsigned short v;
            if (r < 40)       v = f2bf(W1[r * cHID + n]);
            else if (r < 72)  v = f2bf(W1[(104 + r - 40) * cHID + n]);
            else              v = 0;
            int k = (r < 40) ? r : (r < 72 ? 296 + (r - 40) : 328 + (r - 72));
            Btc[n * cKF + k] = v;
            return;
        }
        i -= 12288;
        if (i < 16384) {            // Wt2
            int n = i >> 7, k = i & 127;
            Wt2[n * cHID + k] = f2bf(W2[k * cHID + n]);
            return;
        }
        i -= 16384;
        if (i < 6144) {             // Wt3 (48 x 128, n>=40 zero)
            int n = i >> 7, k = i & 127;
            Wt3[n * cHID + k] = (n < cNUM_CLASSES) ? f2bf(W3[k * cNUM_CLASSES + n]) : 0;
        }
        return;
    }
    if (b < 456) {                  // Wc[kf][n] = sum_j Wf[kf][j] * W1[40+j][n]
        int i = (b - 392) * 256 + tid;
        int kf = i >> 7, n = i & 127;
        float s = 0.f;
        #pragma unroll 8
        for (int j = 0; j < cFEAT_HID; ++j)
            s += Wf[kf * cFEAT_HID + j] * W1[(40 + j) * cHID + n];
        Btc[n * cKF + 40 + kf] = f2bf(s);
        return;
    }
    // bias2 + desc init
    if (tid < cHID) {
        float s = 0.f;
        #pragma unroll 8
        for (int j = 0; j < cFEAT_HID; ++j)
            s += bfv[j] * W1[(40 + j) * cHID + tid];
        bias2[tid] = s;
    } else if (tid - 128 < cSCANB) {
        desc[tid - 128] = 0;
    }
}

// ---------------- mega_scan: merge copies, chunk-prefix rewrite, rowptr, dinv, degidx ----------------
__global__ __launch_bounds__(256) void mega_scan_kernel(unsigned* __restrict__ partial,
                                                        int* __restrict__ rowptr,
                                                        float* __restrict__ dinv,
                                                        int* __restrict__ degidx,
                                                        int* __restrict__ desc) {
    const int b = blockIdx.x, tid = threadIdx.x;
    const int w = b * 256 + tid;
    unsigned slo = 0, shi = 0, plo = 0, phi = 0;
    if (w < cWORDS) {
        const unsigned* ps = partial + w;
        for (int c = 0; c < cNCHUNK; ++c) {
            unsigned v = ps[(size_t)c * cWORDS];
            slo += v & 0xFFFFu; shi += v >> 16;
        }
        unsigned* pd = partial + (size_t)cNCHUNK * cWORDS + w;
        for (int c = 0; c < cNCHUNK; ++c) {
            unsigned v = pd[(size_t)c * cWORDS];
            pd[(size_t)c * cWORDS] = plo | (phi << 16);   // per-chunk prefix (fits u16)
            plo += v & 0xFFFFu; phi += v >> 16;
        }
        int d0 = (int)(slo + plo), d1 = (int)(shi + phi);
        degidx[2 * w]     = d0 > cMAX_DEG - 1 ? cMAX_DEG - 1 : d0;
        degidx[2 * w + 1] = d1 > cMAX_DEG - 1 ? cMAX_DEG - 1 : d1;
    }
    __shared__ int s[256];
    int tot = (int)(plo + phi);
    s[tid] = tot;
    __syncthreads();
    #pragma unroll
    for (int off = 1; off < 256; off <<= 1) {
        int t = (tid >= off) ? s[tid - off] : 0;
        __syncthreads();
        s[tid] += t;
        __syncthreads();
    }
    int ex_local = s[tid] - tot;
    int block_total = s[255];
    if (tid == 0) atomicExch(&desc[b], block_total + 1);
    if (tid < b) {
        int v;
        do { v = atomicAdd(&desc[tid], 0); } while (v == 0);
        s[tid] = v - 1;
    }
    __syncthreads();
    if (tid >= b) s[tid] = 0;
    __syncthreads();
    #pragma unroll
    for (int off = 128; off > 0; off >>= 1) {
        if (tid < off) s[tid] += s[tid + off];
        __syncthreads();
    }
    int base = s[0] + ex_local;
    if (w < cWORDS) {
        rowptr[2 * w]     = base;
        rowptr[2 * w + 1] = base + (int)plo;
        dinv[2 * w]     = rsqrtf((float)(plo + 1));
        dinv[2 * w + 1] = rsqrtf((float)(phi + 1));
    }
    if (b == 0 && tid == 0) rowptr[cN] = cE;
}

// ---------------- merged: CSR scatter (blocks 0..127) + fused conv1 GEMM (R5-proven) ----------------
__global__ __launch_bounds__(256) void scatter_gemm_kernel(const int* __restrict__ edge,
                                                           const unsigned* __restrict__ partial,
                                                           const int* __restrict__ rowptr,
                                                           int* __restrict__ adj,
                                                           const float* __restrict__ logits,
                                                           const float* __restrict__ features,
                                                           const float* __restrict__ deg_table,
                                                           const int* __restrict__ degidx,
                                                           const unsigned short* __restrict__ Btc,
                                                           const float* __restrict__ bias2,
                                                           const float* __restrict__ dinv,
                                                           unsigned short* __restrict__ out) {
    __shared__ unsigned shmem[cHWORDS];   // 50 KB, shared by both roles
    const int b = blockIdx.x, tid = threadIdx.x;

    if (b < 128) {
        // ---- scatter role (LDS prefix, no global atomics) ----
        const int cb = b & (cNCHUNK - 1);
        const int half = (b >> 6) & 1;
        const int wbase = half * cHWORDS;
        const unsigned* pp = partial + ((size_t)cNCHUNK + cb) * cWORDS + wbase;
        for (int i = tid; i < cHWORDS; i += 256) shmem[i] = pp[i];
        __syncthreads();
        const int* srcs = edge + (size_t)cb * cCHUNK;
        const int* dsts = edge + cE + (size_t)cb * cCHUNK;
        const int lo = half * (cN / 2), hi = lo + cN / 2;
        for (int i = tid; i < cCHUNK; i += 256) {
            int d = dsts[i];
            if (d >= lo && d < hi) {
                int sh = (d & 1) * 16;
                unsigned old = atomicAdd(&shmem[(d >> 1) - wbase], 1u << sh);
                int off = (int)((old >> sh) & 0xFFFFu);
                adj[rowptr[d] + off] = srcs[i];
            }
        }
        return;
    }

    // ---- fused conv1 GEMM role ----
    unsigned short* As = (unsigned short*)shmem;        // 64 x cAST1 = 46,080 B

    const int gb = b - 128;
    const int rowbase = gb * 64;
    const int arow = tid >> 2;
    const int akq = (tid & 3) * 8;
    int gr = rowbase + arow;
    if (gr > cN - 1) gr = cN - 1;
    const int didx = degidx[gr];

    // bulk staging: all 11 K-segments, issued back-to-back (22 float4 loads/thread)
    #pragma unroll
    for (int k0 = 0; k0 < cKF; k0 += 32) {
        #pragma unroll
        for (int h = 0; h < 2; ++h) {
            int k4 = k0 + akq + h * 4;
            float4 v = make_float4(0.f, 0.f, 0.f, 0.f);
            if (k4 < 40)       v = *(const float4*)&logits[(size_t)gr * cNUM_CLASSES + k4];
            else if (k4 < 296) v = *(const float4*)&features[(size_t)gr * cFEAT_DIM + (k4 - 40)];
            else if (k4 < 328) v = *(const float4*)&deg_table[didx * cDEG_HID + (k4 - 296)];
            unsigned long long p = (unsigned long long)f2bf(v.x)
                                 | ((unsigned long long)f2bf(v.y) << 16)
                                 | ((unsigned long long)f2bf(v.z) << 32)
                                 | ((unsigned long long)f2bf(v.w) << 48);
            *(unsigned long long*)&As[arow * cAST1 + k4] = p;
        }
    }
    __syncthreads();

    const int wave = tid >> 6;
    const int lane = tid & 63;
    const int m15 = lane & 15;
    const int q = lane >> 4;

    float4_t acc[4][2];
    #pragma unroll
    for (int mt = 0; mt < 4; ++mt)
        #pragma unroll
        for (int tt = 0; tt < 2; ++tt)
            acc[mt][tt] = (float4_t){0.f, 0.f, 0.f, 0.f};

    #pragma unroll
    for (int k0 = 0; k0 < cKF; k0 += 32) {
        short8_t bfr[2];
        #pragma unroll
        for (int tt = 0; tt < 2; ++tt)
            bfr[tt] = *(const short8_t*)&Btc[(size_t)((wave * 2 + tt) * 16 + m15) * cKF + k0 + q * 8];
        #pragma unroll
        for (int mt = 0; mt < 4; ++mt) {
            short8_t a = *(const short8_t*)&As[(mt * 16 + m15) * cAST1 + k0 + q * 8];
            acc[mt][0] = __builtin_amdgcn_mfma_f32_16x16x32_bf16(a, bfr[0], acc[mt][0], 0, 0, 0);
            acc[mt][1] = __builtin_amdgcn_mfma_f32_16x16x32_bf16(a, bfr[1], acc[mt][1], 0, 0, 0);
        }
    }

    #pragma unroll
    for (int mt = 0; mt < 4; ++mt) {
        #pragma unroll
        for (int r = 0; r < 4; ++r) {
            int row = rowbase + mt * 16 + q * 4 + r;
            if (row >= cN) continue;
            float dr = dinv[row];
            #pragma unroll
            for (int tt = 0; tt < 2; ++tt) {
                int col = (wave * 2 + tt) * 16 + m15;
                out[((size_t)(col >> 5) * cN + row) * 32 + (col & 31)] =
                    f2bf((acc[mt][tt][r] + bias2[col]) * dr);
            }
        }
    }
}

// ---------------- fused aggregate + GEMM ----------------
// Block = 64 output rows. Phase 1 (512 thr = 64 rows x 8): aggregate planar tin over edges,
// x = relu(di*(sum+self)+bias) -> LDS bf16 [64][136]. Phase 2: GEMM x @ Wt^T (B-fragments
// direct from L2-resident Wt), dinv-scaled epilogue (planar [4][N][32] or flat [N][40]).
template <int NCOL, bool FLAT>
__global__ __launch_bounds__(512) void agg_gemm(const unsigned short* __restrict__ tin,
                                                const int* __restrict__ rowptr,
                                                const int* __restrict__ adj,
                                                const float* __restrict__ dinv,
                                                const float* __restrict__ bias,
                                                const unsigned short* __restrict__ Wt,
                                                unsigned short* __restrict__ outp) {
    constexpr int AST = 136;
    __shared__ unsigned short As[64 * AST];   // 17.4 KB
    const int tid = threadIdx.x;
    const int rowbase = blockIdx.x * 64;

    {   // ---- aggregate phase: 8 threads/row, 16 ch each ----
        const int lrow = tid >> 3;
        const int sub = tid & 7;
        const int g = sub >> 1;              // plane 0..3
        const int cl = (sub & 1) * 16;       // 0 or 16 within plane
        const int row = rowbase + lrow;
        unsigned short* dst = &As[lrow * AST + sub * 16];
        if (row < cN) {
            const unsigned short* tp = tin + (size_t)g * cN * 32 + cl;
            const float di = dinv[row];
            int e = rowptr[row];
            const int end = rowptr[row + 1];
            float aA[16], aB[16];
            #pragma unroll
            for (int k = 0; k < 16; ++k) { aA[k] = 0.f; aB[k] = 0.f; }
            for (; e + 1 < end; e += 2) {
                int j0 = adj[e], j1 = adj[e + 1];
                ushort8_t u00 = *(const ushort8_t*)&tp[(size_t)j0 * 32];
                ushort8_t u01 = *(const ushort8_t*)&tp[(size_t)j0 * 32 + 8];
                ushort8_t u10 = *(const ushort8_t*)&tp[(size_t)j1 * 32];
                ushort8_t u11 = *(const ushort8_t*)&tp[(size_t)j1 * 32 + 8];
                #pragma unroll
                for (int k = 0; k < 8; ++k) {
                    aA[k]     += bf2f(u00[k]);
                    aA[k + 8] += bf2f(u01[k]);
                    aB[k]     += bf2f(u10[k]);
                    aB[k + 8] += bf2f(u11[k]);
                }
            }
            if (e < end) {
                int j0 = adj[e];
                ushort8_t u00 = *(const ushort8_t*)&tp[(size_t)j0 * 32];
                ushort8_t u01 = *(const ushort8_t*)&tp[(size_t)j0 * 32 + 8];
                #pragma unroll
                for (int k = 0; k < 8; ++k) {
                    aA[k]     += bf2f(u00[k]);
                    aA[k + 8] += bf2f(u01[k]);
                }
            }
            ushort8_t s0 = *(const ushort8_t*)&tp[(size_t)row * 32];
            ushort8_t s1 = *(const ushort8_t*)&tp[(size_t)row * 32 + 8];
            ushort8_t o0, o1;
            #pragma unroll
            for (int k = 0; k < 8; ++k) {
                float r0 = di * ((aA[k] + aB[k]) + bf2f(s0[k])) + bias[g * 32 + cl + k];
                float r1 = di * ((aA[k + 8] + aB[k + 8]) + bf2f(s1[k])) + bias[g * 32 + cl + 8 + k];
                o0[k] = f2bf(fmaxf(r0, 0.f));
                o1[k] = f2bf(fmaxf(r1, 0.f));
            }
            *(ushort8_t*)&dst[0] = o0;
            *(ushort8_t*)&dst[8] = o1;
        } else {
            ushort8_t z = (ushort8_t){0, 0, 0, 0, 0, 0, 0, 0};
            *(ushort8_t*)&dst[0] = z;
            *(ushort8_t*)&dst[8] = z;
        }
    }
    __syncthreads();

    // ---- GEMM phase: 8 waves; wave = output col-tile; B-fragments from L2 ----
    constexpr int NTILE = (NCOL + 15) / 16;
    const int wave = tid >> 6;
    const int lane = tid & 63;
    const int m15 = lane & 15;
    const int q = lane >> 4;

    if (wave < NTILE) {
        const int coln = wave * 16 + m15;
        float4_t acc[4];
        #pragma unroll
        for (int mt = 0; mt < 4; ++mt) acc[mt] = (float4_t){0.f, 0.f, 0.f, 0.f};
        #pragma unroll
        for (int k0 = 0; k0 < cHID; k0 += 32) {
            short8_t bfr = *(const short8_t*)&Wt[(size_t)coln * cHID + k0 + q * 8];
            #pragma unroll
            for (int mt = 0; mt < 4; ++mt) {
                short8_t a = *(const short8_t*)&As[(mt * 16 + m15) * AST + k0 + q * 8];
                acc[mt] = __builtin_amdgcn_mfma_f32_16x16x32_bf16(a, bfr, acc[mt], 0, 0, 0);
            }
        }
        #pragma unroll
        for (int mt = 0; mt < 4; ++mt) {
            #pragma unroll
            for (int r = 0; r < 4; ++r) {
                int row = rowbase + mt * 16 + q * 4 + r;
                if (row >= cN) continue;
                unsigned short v = f2bf(acc[mt][r] * dinv[row]);
                if (FLAT) {
                    if (coln < cNUM_CLASSES)
                        outp[(size_t)row * cNUM_CLASSES + coln] = v;
                } else {
                    outp[((size_t)(coln >> 5) * cN + row) * 32 + (coln & 31)] = v;
                }
            }
        }
    }
}

// ---------------- GCN aggregate over pre-scaled bf16 t' (40 ch, flat, final, fp32 out) ----------------
__global__ __launch_bounds__(128) void agg_bf40(const unsigned short* __restrict__ t,
                                                const int* __restrict__ rowptr,
                                                const int* __restrict__ adj,
                                                const float* __restrict__ dinv,
                                                const float* __restrict__ b,
                                                float* __restrict__ out) {
    const int tid = threadIdx.x;
    const int lane = tid & 7;
    const int row = blockIdx.x * 16 + (tid >> 3);
    if (row >= cN) return;
    const int c = lane * 8;
    if (c >= cNUM_CLASSES) return;
    const float di = dinv[row];
    int e = rowptr[row];
    const int end = rowptr[row + 1];
    float a0[8], a1[8], a2[8], a3[8];
    #pragma unroll
    for (int k = 0; k < 8; ++k) { a0[k] = 0.f; a1[k] = 0.f; a2[k] = 0.f; a3[k] = 0.f; }
    for (; e + 3 < end; e += 4) {
        int j0 = adj[e], j1 = adj[e + 1], j2 = adj[e + 2], j3 = adj[e + 3];
        ushort8_t t0 = *(const ushort8_t*)&t[(size_t)j0 * cNUM_CLASSES + c];
        ushort8_t t1 = *(const ushort8_t*)&t[(size_t)j1 * cNUM_CLASSES + c];
        ushort8_t t2 = *(const ushort8_t*)&t[(size_t)j2 * cNUM_CLASSES + c];
        ushort8_t t3 = *(const ushort8_t*)&t[(size_t)j3 * cNUM_CLASSES + c];
        #pragma unroll
        for (int k = 0; k < 8; ++k) {
            a0[k] += bf2f(t0[k]);
            a1[k] += bf2f(t1[k]);
            a2[k] += bf2f(t2[k]);
            a3[k] += bf2f(t3[k]);
        }
    }
    for (; e < end; ++e) {
        int j0 = adj[e];
        ushort8_t t0 = *(const ushort8_t*)&t[(size_t)j0 * cNUM_CLASSES + c];
        #pragma unroll
        for (int k = 0; k < 8; ++k) a0[k] += bf2f(t0[k]);
    }
    ushort8_t ts = *(const ushort8_t*)&t[(size_t)row * cNUM_CLASSES + c];
    float r[8];
    #pragma unroll
    for (int k = 0; k < 8; ++k)
        r[k] = di * (((a0[k] + a1[k]) + (a2[k] + a3[k])) + bf2f(ts[k])) + b[c + k];
    float4 v0 = make_float4(r[0], r[1], r[2], r[3]);
    float4 v1 = make_float4(r[4], r[5], r[6], r[7]);
    *(float4*)&out[(size_t)row * cNUM_CLASSES + c] = v0;
    *(float4*)&out[(size_t)row * cNUM_CLASSES + c + 4] = v1;
}

extern "C" void kernel_launch(void* const* d_in, const int* in_sizes, int n_in,
                              void* d_out, int out_size, void* d_ws, size_t ws_size,
                              hipStream_t stream) {
    const float* logits    = (const float*)d_in[0];
    const float* features  = (const float*)d_in[1];
    const int*   edge      = (const int*)d_in[2];
    const float* Wf        = (const float*)d_in[3];
    const float* bfv       = (const float*)d_in[4];
    const float* deg_table = (const float*)d_in[5];
    const float* W1        = (const float*)d_in[6];
    const float* b1        = (const float*)d_in[7];
    const float* W2        = (const float*)d_in[8];
    const float* b2        = (const float*)d_in[9];
    const float* W3        = (const float*)d_in[10];
    const float* b3        = (const float*)d_in[11];
    float* out = (float*)d_out;

    // workspace carve-up (16B-aligned sections)
    int* rowptr    = (int*)d_ws;                 // N+1 (padded)
    int* adj       = rowptr + cN + 16;           // E
    int* desc      = adj + cE;                   // 128
    int* degidx    = desc + 128;                 // N
    float* dinv    = (float*)(degidx + cN);      // N
    float* bias2   = dinv + cN;                  // 128
    unsigned short* tb  = (unsigned short*)(bias2 + 128);          // N*128 bf16 (planar [4][N][32] / flat40)
    unsigned short* hb  = tb + (size_t)cN * cHID;                  // N*128 bf16 (planar [4][N][32])
    unsigned short* Btc = hb + (size_t)cN * cHID;                  // 128*352
    unsigned short* Wt2 = Btc + 128 * cKF;                         // 128*128
    unsigned short* Wt3 = Wt2 + 128 * cHID;                        // 48*128
    unsigned* partial = (unsigned*)(Wt3 + 48 * cHID);              // 2*64*25000 u32

    // histograms + all weight preprocessing + desc init (one launch, 457 blocks)
    prep_kernel<<<457, 256, 0, stream>>>(edge, partial, Wf, bfv, W1, W2, W3,
                                         Btc, Wt2, Wt3, bias2, desc);

    // merged scan: chunk-prefix rewrite, rowptr, dinv, degidx (one launch, parallel lookback)
    mega_scan_kernel<<<cSCANB, 256, 0, stream>>>(partial, rowptr, dinv, degidx, desc);

    constexpr int MB = (cN + 63) / 64; // 782

    // merged: CSR scatter (128 blocks) + fused conv1 GEMM (782 blocks) -> tb planar
    scatter_gemm_kernel<<<128 + MB, 256, 0, stream>>>(edge, partial, rowptr, adj,
                                                      logits, features, deg_table, degidx,
                                                      Btc, bias2, dinv, tb);

    // fused agg1 + conv2: reads tb planar, writes hb planar
    agg_gemm<cHID, false><<<MB, 512, 0, stream>>>(tb, rowptr, adj, dinv, b1, Wt2, hb);

    // fused agg2 + conv3: reads hb planar, writes tb flat [N][40]
    agg_gemm<48, true><<<MB, 512, 0, stream>>>(hb, rowptr, adj, dinv, b2, Wt3, tb);

    // final aggregate (fp32 out)
    agg_bf40<<<(cN + 15) / 16, 128, 0, stream>>>(tb, rowptr, adj, dinv, b3, out);
}

// Round 11
// 304.438 us; speedup vs baseline: 1.0335x; 1.0335x over previous
//
#include <hip/hip_runtime.h>
#include <hip/hip_bf16.h>

// Problem constants (match reference)
constexpr int cN = 50000;
constexpr int cE = 800000;
constexpr int cNUM_CLASSES = 40;
constexpr int cFEAT_DIM = 256;
constexpr int cFEAT_HID = 64;
constexpr int cDEG_HID = 32;
constexpr int cHID = 128;
constexpr int cMAX_DEG = 256;
constexpr int cKF = 352;                // fused conv1 K: 40 logits + 256 feat + 32 deg + 24 pad
constexpr int cAST1 = 360;              // conv1 LDS A stride (pad +8)

// LDS-histogram CSR build parameters
constexpr int cNCHUNK = 64;             // edge chunks (= copies per histogram)
constexpr int cCHUNK  = cE / cNCHUNK;   // 12500 edges per chunk (exact)
constexpr int cWORDS  = cN / 2;         // 25000 packed u16-pair words per histogram
constexpr int cHWORDS = cWORDS / 2;     // 12500 words per node-range half (50 KB LDS)
constexpr int cSCANB  = (cWORDS + 255) / 256; // 98 blocks for mega_scan

typedef unsigned short ushort8_t __attribute__((ext_vector_type(8)));
typedef short short8_t __attribute__((ext_vector_type(8)));
typedef float float4_t __attribute__((ext_vector_type(4)));

__device__ __forceinline__ unsigned short f2bf(float f) {
    unsigned u = __builtin_bit_cast(unsigned, f);
    u += 0x7fff + ((u >> 16) & 1); // RNE
    return (unsigned short)(u >> 16);
}
__device__ __forceinline__ float bf2f(unsigned short s) {
    unsigned u = ((unsigned)s) << 16;
    return __builtin_bit_cast(float, u);
}

// ---------------- prep: histograms + all weight preprocessing + desc init (R5-proven) ----------------
__global__ __launch_bounds__(256) void prep_kernel(const int* __restrict__ edge,
                                                   unsigned* __restrict__ partial,
                                                   const float* __restrict__ Wf,
                                                   const float* __restrict__ bfv,
                                                   const float* __restrict__ W1,
                                                   const float* __restrict__ W2,
                                                   const float* __restrict__ W3,
                                                   unsigned short* __restrict__ Btc,
                                                   unsigned short* __restrict__ Wt2,
                                                   unsigned short* __restrict__ Wt3,
                                                   float* __restrict__ bias2,
                                                   int* __restrict__ desc) {
    __shared__ unsigned lds[cHWORDS];
    const int b = blockIdx.x, tid = threadIdx.x;
    if (b < 256) {
        const int cb = b & (cNCHUNK - 1);
        const int half = (b >> 6) & 1;
        const int which = b >> 7;
        for (int i = tid; i < cHWORDS; i += 256) lds[i] = 0;
        __syncthreads();
        const int* ids = edge + (size_t)which * cE + (size_t)cb * cCHUNK;
        const int lo = half * (cN / 2), hi = lo + cN / 2;
        const int wbase = half * cHWORDS;
        for (int i = tid; i < cCHUNK; i += 256) {
            int v = ids[i];
            if (v >= lo && v < hi)
                atomicAdd(&lds[(v >> 1) - wbase], 1u << ((v & 1) * 16));
        }
        __syncthreads();
        unsigned* outp = partial + ((size_t)which * cNCHUNK + cb) * cWORDS + wbase;
        for (int i = tid; i < cHWORDS; i += 256) outp[i] = lds[i];
        return;
    }
    if (b < 392) {
        int i = (b - 256) * 256 + tid;
        if (i < 12288) {            // Btc: logits rows, deg rows, zero pad
            int n = i / 96, r = i - (i / 96) * 96;
            unsigned short v;
            if (r < 40)       v = f2bf(W1[r * cHID + n]);
            else if (r < 72)  v = f2bf(W1[(104 + r - 40) * cHID + n]);
            else              v = 0;
            int k = (r < 40) ? r : (r < 72 ? 296 + (r - 40) : 328 + (r - 72));
            Btc[n * cKF + k] = v;
            return;
        }
        i -= 12288;
        if (i < 16384) {            // Wt2
            int n = i >> 7, k = i & 127;
            Wt2[n * cHID + k] = f2bf(W2[k * cHID + n]);
            return;
        }
        i -= 16384;
        if (i < 6144) {             // Wt3 (48 x 128, n>=40 zero)
            int n = i >> 7, k = i & 127;
            Wt3[n * cHID + k] = (n < cNUM_CLASSES) ? f2bf(W3[k * cNUM_CLASSES + n]) : 0;
        }
        return;
    }
    if (b < 456) {                  // Wc[kf][n] = sum_j Wf[kf][j] * W1[40+j][n]
        int i = (b - 392) * 256 + tid;
        int kf = i >> 7, n = i & 127;
        float s = 0.f;
        #pragma unroll 8
        for (int j = 0; j < cFEAT_HID; ++j)
            s += Wf[kf * cFEAT_HID + j] * W1[(40 + j) * cHID + n];
        Btc[n * cKF + 40 + kf] = f2bf(s);
        return;
    }
    // bias2 + desc init
    if (tid < cHID) {
        float s = 0.f;
        #pragma unroll 8
        for (int j = 0; j < cFEAT_HID; ++j)
            s += bfv[j] * W1[(40 + j) * cHID + tid];
        bias2[tid] = s;
    } else if (tid - 128 < cSCANB) {
        desc[tid - 128] = 0;
    }
}

// ---------------- mega_scan: merge copies, chunk-prefix rewrite, rowptr, dinv, degidx ----------------
__global__ __launch_bounds__(256) void mega_scan_kernel(unsigned* __restrict__ partial,
                                                        int* __restrict__ rowptr,
                                                        float* __restrict__ dinv,
                                                        int* __restrict__ degidx,
                                                        int* __restrict__ desc) {
    const int b = blockIdx.x, tid = threadIdx.x;
    const int w = b * 256 + tid;
    unsigned slo = 0, shi = 0, plo = 0, phi = 0;
    if (w < cWORDS) {
        const unsigned* ps = partial + w;
        for (int c = 0; c < cNCHUNK; ++c) {
            unsigned v = ps[(size_t)c * cWORDS];
            slo += v & 0xFFFFu; shi += v >> 16;
        }
        unsigned* pd = partial + (size_t)cNCHUNK * cWORDS + w;
        for (int c = 0; c < cNCHUNK; ++c) {
            unsigned v = pd[(size_t)c * cWORDS];
            pd[(size_t)c * cWORDS] = plo | (phi << 16);   // per-chunk prefix (fits u16)
            plo += v & 0xFFFFu; phi += v >> 16;
        }
        int d0 = (int)(slo + plo), d1 = (int)(shi + phi);
        degidx[2 * w]     = d0 > cMAX_DEG - 1 ? cMAX_DEG - 1 : d0;
        degidx[2 * w + 1] = d1 > cMAX_DEG - 1 ? cMAX_DEG - 1 : d1;
    }
    __shared__ int s[256];
    int tot = (int)(plo + phi);
    s[tid] = tot;
    __syncthreads();
    #pragma unroll
    for (int off = 1; off < 256; off <<= 1) {
        int t = (tid >= off) ? s[tid - off] : 0;
        __syncthreads();
        s[tid] += t;
        __syncthreads();
    }
    int ex_local = s[tid] - tot;
    int block_total = s[255];
    if (tid == 0) atomicExch(&desc[b], block_total + 1);
    if (tid < b) {
        int v;
        do { v = atomicAdd(&desc[tid], 0); } while (v == 0);
        s[tid] = v - 1;
    }
    __syncthreads();
    if (tid >= b) s[tid] = 0;
    __syncthreads();
    #pragma unroll
    for (int off = 128; off > 0; off >>= 1) {
        if (tid < off) s[tid] += s[tid + off];
        __syncthreads();
    }
    int base = s[0] + ex_local;
    if (w < cWORDS) {
        rowptr[2 * w]     = base;
        rowptr[2 * w + 1] = base + (int)plo;
        dinv[2 * w]     = rsqrtf((float)(plo + 1));
        dinv[2 * w + 1] = rsqrtf((float)(phi + 1));
    }
    if (b == 0 && tid == 0) rowptr[cN] = cE;
}

// ---------------- merged: CSR scatter (blocks 0..127) + fused conv1 GEMM (R5-proven) ----------------
__global__ __launch_bounds__(256) void scatter_gemm_kernel(const int* __restrict__ edge,
                                                           const unsigned* __restrict__ partial,
                                                           const int* __restrict__ rowptr,
                                                           int* __restrict__ adj,
                                                           const float* __restrict__ logits,
                                                           const float* __restrict__ features,
                                                           const float* __restrict__ deg_table,
                                                           const int* __restrict__ degidx,
                                                           const unsigned short* __restrict__ Btc,
                                                           const float* __restrict__ bias2,
                                                           const float* __restrict__ dinv,
                                                           unsigned short* __restrict__ out) {
    __shared__ unsigned shmem[cHWORDS];   // 50 KB, shared by both roles
    const int b = blockIdx.x, tid = threadIdx.x;

    if (b < 128) {
        // ---- scatter role (LDS prefix, no global atomics) ----
        const int cb = b & (cNCHUNK - 1);
        const int half = (b >> 6) & 1;
        const int wbase = half * cHWORDS;
        const unsigned* pp = partial + ((size_t)cNCHUNK + cb) * cWORDS + wbase;
        for (int i = tid; i < cHWORDS; i += 256) shmem[i] = pp[i];
        __syncthreads();
        const int* srcs = edge + (size_t)cb * cCHUNK;
        const int* dsts = edge + cE + (size_t)cb * cCHUNK;
        const int lo = half * (cN / 2), hi = lo + cN / 2;
        for (int i = tid; i < cCHUNK; i += 256) {
            int d = dsts[i];
            if (d >= lo && d < hi) {
                int sh = (d & 1) * 16;
                unsigned old = atomicAdd(&shmem[(d >> 1) - wbase], 1u << sh);
                int off = (int)((old >> sh) & 0xFFFFu);
                adj[rowptr[d] + off] = srcs[i];
            }
        }
        return;
    }

    // ---- fused conv1 GEMM role ----
    unsigned short* As = (unsigned short*)shmem;        // 64 x cAST1 = 46,080 B

    const int gb = b - 128;
    const int rowbase = gb * 64;
    const int arow = tid >> 2;
    const int akq = (tid & 3) * 8;
    int gr = rowbase + arow;
    if (gr > cN - 1) gr = cN - 1;
    const int didx = degidx[gr];

    // bulk staging: all 11 K-segments, issued back-to-back (22 float4 loads/thread)
    #pragma unroll
    for (int k0 = 0; k0 < cKF; k0 += 32) {
        #pragma unroll
        for (int h = 0; h < 2; ++h) {
            int k4 = k0 + akq + h * 4;
            float4 v = make_float4(0.f, 0.f, 0.f, 0.f);
            if (k4 < 40)       v = *(const float4*)&logits[(size_t)gr * cNUM_CLASSES + k4];
            else if (k4 < 296) v = *(const float4*)&features[(size_t)gr * cFEAT_DIM + (k4 - 40)];
            else if (k4 < 328) v = *(const float4*)&deg_table[didx * cDEG_HID + (k4 - 296)];
            unsigned long long p = (unsigned long long)f2bf(v.x)
                                 | ((unsigned long long)f2bf(v.y) << 16)
                                 | ((unsigned long long)f2bf(v.z) << 32)
                                 | ((unsigned long long)f2bf(v.w) << 48);
            *(unsigned long long*)&As[arow * cAST1 + k4] = p;
        }
    }
    __syncthreads();

    const int wave = tid >> 6;
    const int lane = tid & 63;
    const int m15 = lane & 15;
    const int q = lane >> 4;

    float4_t acc[4][2];
    #pragma unroll
    for (int mt = 0; mt < 4; ++mt)
        #pragma unroll
        for (int tt = 0; tt < 2; ++tt)
            acc[mt][tt] = (float4_t){0.f, 0.f, 0.f, 0.f};

    #pragma unroll
    for (int k0 = 0; k0 < cKF; k0 += 32) {
        short8_t bfr[2];
        #pragma unroll
        for (int tt = 0; tt < 2; ++tt)
            bfr[tt] = *(const short8_t*)&Btc[(size_t)((wave * 2 + tt) * 16 + m15) * cKF + k0 + q * 8];
        #pragma unroll
        for (int mt = 0; mt < 4; ++mt) {
            short8_t a = *(const short8_t*)&As[(mt * 16 + m15) * cAST1 + k0 + q * 8];
            acc[mt][0] = __builtin_amdgcn_mfma_f32_16x16x32_bf16(a, bfr[0], acc[mt][0], 0, 0, 0);
            acc[mt][1] = __builtin_amdgcn_mfma_f32_16x16x32_bf16(a, bfr[1], acc[mt][1], 0, 0, 0);
        }
    }

    #pragma unroll
    for (int mt = 0; mt < 4; ++mt) {
        #pragma unroll
        for (int r = 0; r < 4; ++r) {
            int row = rowbase + mt * 16 + q * 4 + r;
            if (row >= cN) continue;
            float dr = dinv[row];
            #pragma unroll
            for (int tt = 0; tt < 2; ++tt) {
                int col = (wave * 2 + tt) * 16 + m15;
                out[((size_t)(col >> 5) * cN + row) * 32 + (col & 31)] =
                    f2bf((acc[mt][tt][r] + bias2[col]) * dr);
            }
        }
    }
}

// ---------------- MFMA GEMM: planar A [4][N][32], bulk-staged LDS (R5-proven) ----------------
template <int NT, int OSTR, int OUTC, bool POUT>
__global__ __launch_bounds__(256) void mfma_gemm(const unsigned short* __restrict__ A,
                                                 const unsigned short* __restrict__ Bt,
                                                 const float* __restrict__ dinv,
                                                 unsigned short* __restrict__ out) {
    constexpr int KTOT = 128;
    constexpr int AST = KTOT + 8;       // padded stride
    constexpr int KQ = KTOT / 8;        // 16 chunks of 8 ch
    __shared__ unsigned short As[64 * AST];
    __shared__ unsigned short Bs[NT * 16 * AST];

    const int tid = threadIdx.x;
    const int rowbase = blockIdx.x * 64;

    for (int i = tid; i < 64 * KQ; i += 256) {
        int r = i / KQ, c8 = i % KQ;
        int gr = rowbase + r;
        if (gr > cN - 1) gr = cN - 1;
        *(ushort8_t*)&As[r * AST + c8 * 8] =
            *(const ushort8_t*)&A[((size_t)(c8 >> 2) * cN + gr) * 32 + (c8 & 3) * 8];
    }
    for (int i = tid; i < NT * 16 * KQ; i += 256) {
        int n = i / KQ, kq = (i % KQ) * 8;
        *(ushort8_t*)&Bs[n * AST + kq] = *(const ushort8_t*)&Bt[(size_t)n * KTOT + kq];
    }
    __syncthreads();

    const int wave = tid >> 6;
    const int lane = tid & 63;
    const int m15 = lane & 15;
    const int q = lane >> 4;

    float4_t acc[NT];
    #pragma unroll
    for (int t = 0; t < NT; ++t) acc[t] = (float4_t){0.f, 0.f, 0.f, 0.f};

    #pragma unroll
    for (int k0 = 0; k0 < KTOT; k0 += 32) {
        short8_t a = *(const short8_t*)&As[(wave * 16 + m15) * AST + k0 + q * 8];
        #pragma unroll
        for (int t = 0; t < NT; ++t) {
            short8_t b = *(const short8_t*)&Bs[(t * 16 + m15) * AST + k0 + q * 8];
            acc[t] = __builtin_amdgcn_mfma_f32_16x16x32_bf16(a, b, acc[t], 0, 0, 0);
        }
    }

    #pragma unroll
    for (int r = 0; r < 4; ++r) {
        int row = rowbase + wave * 16 + q * 4 + r;
        if (row >= cN) continue;
        float dr = dinv[row];
        #pragma unroll
        for (int t = 0; t < NT; ++t) {
            int col = t * 16 + m15;
            if (OUTC % 16 != 0 && col >= OUTC) continue;
            unsigned short v = f2bf(acc[t][r] * dr);
            if (POUT)
                out[((size_t)(col >> 5) * cN + row) * 32 + (col & 31)] = v;
            else
                out[(size_t)row * OSTR + col] = v;
        }
    }
}

// ---------------- channel-split GCN aggregate, ONE GROUP PER LAUNCH (temporal L2 locality) ----
// During a launch every gather on every XCD targets one 3.2 MB plane -> fits any 4 MB L2.
template <bool RELU>
__global__ __launch_bounds__(256) void agg_cs(const unsigned short* __restrict__ t,
                                              const int* __restrict__ rowptr,
                                              const int* __restrict__ adj,
                                              const float* __restrict__ dinv,
                                              const float* __restrict__ bias,
                                              unsigned short* __restrict__ outb,
                                              int g) {
    const int b = blockIdx.x, tid = threadIdx.x;
    const int row = b * 64 + (tid >> 2);
    if (row >= cN) return;
    const int cl = (tid & 3) * 8;
    const float di = dinv[row];
    const unsigned short* tp = t + (size_t)g * cN * 32;
    int e = rowptr[row];
    const int end = rowptr[row + 1];
    float a0[8], a1[8], a2[8], a3[8];
    #pragma unroll
    for (int k = 0; k < 8; ++k) { a0[k] = 0.f; a1[k] = 0.f; a2[k] = 0.f; a3[k] = 0.f; }
    for (; e + 3 < end; e += 4) {
        int j0 = adj[e], j1 = adj[e + 1], j2 = adj[e + 2], j3 = adj[e + 3];
        ushort8_t t0 = *(const ushort8_t*)&tp[(size_t)j0 * 32 + cl];
        ushort8_t t1 = *(const ushort8_t*)&tp[(size_t)j1 * 32 + cl];
        ushort8_t t2 = *(const ushort8_t*)&tp[(size_t)j2 * 32 + cl];
        ushort8_t t3 = *(const ushort8_t*)&tp[(size_t)j3 * 32 + cl];
        #pragma unroll
        for (int k = 0; k < 8; ++k) {
            a0[k] += bf2f(t0[k]);
            a1[k] += bf2f(t1[k]);
            a2[k] += bf2f(t2[k]);
            a3[k] += bf2f(t3[k]);
        }
    }
    for (; e < end; ++e) {
        int j0 = adj[e];
        ushort8_t t0 = *(const ushort8_t*)&tp[(size_t)j0 * 32 + cl];
        #pragma unroll
        for (int k = 0; k < 8; ++k) a0[k] += bf2f(t0[k]);
    }
    ushort8_t ts = *(const ushort8_t*)&tp[(size_t)row * 32 + cl];
    ushort8_t o;
    #pragma unroll
    for (int k = 0; k < 8; ++k) {
        float r = di * (((a0[k] + a1[k]) + (a2[k] + a3[k])) + bf2f(ts[k])) + bias[g * 32 + cl + k];
        if (RELU) r = fmaxf(r, 0.f);
        o[k] = f2bf(r);
    }
    *(ushort8_t*)&outb[((size_t)g * cN + row) * 32 + cl] = o;
}

// ---------------- GCN aggregate over pre-scaled bf16 t' (40 ch, flat, final, fp32 out) ----------------
__global__ __launch_bounds__(128) void agg_bf40(const unsigned short* __restrict__ t,
                                                const int* __restrict__ rowptr,
                                                const int* __restrict__ adj,
                                                const float* __restrict__ dinv,
                                                const float* __restrict__ b,
                                                float* __restrict__ out) {
    const int tid = threadIdx.x;
    const int lane = tid & 7;
    const int row = blockIdx.x * 16 + (tid >> 3);
    if (row >= cN) return;
    const int c = lane * 8;
    if (c >= cNUM_CLASSES) return;
    const float di = dinv[row];
    int e = rowptr[row];
    const int end = rowptr[row + 1];
    float a0[8], a1[8], a2[8], a3[8];
    #pragma unroll
    for (int k = 0; k < 8; ++k) { a0[k] = 0.f; a1[k] = 0.f; a2[k] = 0.f; a3[k] = 0.f; }
    for (; e + 3 < end; e += 4) {
        int j0 = adj[e], j1 = adj[e + 1], j2 = adj[e + 2], j3 = adj[e + 3];
        ushort8_t t0 = *(const ushort8_t*)&t[(size_t)j0 * cNUM_CLASSES + c];
        ushort8_t t1 = *(const ushort8_t*)&t[(size_t)j1 * cNUM_CLASSES + c];
        ushort8_t t2 = *(const ushort8_t*)&t[(size_t)j2 * cNUM_CLASSES + c];
        ushort8_t t3 = *(const ushort8_t*)&t[(size_t)j3 * cNUM_CLASSES + c];
        #pragma unroll
        for (int k = 0; k < 8; ++k) {
            a0[k] += bf2f(t0[k]);
            a1[k] += bf2f(t1[k]);
            a2[k] += bf2f(t2[k]);
            a3[k] += bf2f(t3[k]);
        }
    }
    for (; e < end; ++e) {
        int j0 = adj[e];
        ushort8_t t0 = *(const ushort8_t*)&t[(size_t)j0 * cNUM_CLASSES + c];
        #pragma unroll
        for (int k = 0; k < 8; ++k) a0[k] += bf2f(t0[k]);
    }
    ushort8_t ts = *(const ushort8_t*)&t[(size_t)row * cNUM_CLASSES + c];
    float r[8];
    #pragma unroll
    for (int k = 0; k < 8; ++k)
        r[k] = di * (((a0[k] + a1[k]) + (a2[k] + a3[k])) + bf2f(ts[k])) + b[c + k];
    float4 v0 = make_float4(r[0], r[1], r[2], r[3]);
    float4 v1 = make_float4(r[4], r[5], r[6], r[7]);
    *(float4*)&out[(size_t)row * cNUM_CLASSES + c] = v0;
    *(float4*)&out[(size_t)row * cNUM_CLASSES + c + 4] = v1;
}

extern "C" void kernel_launch(void* const* d_in, const int* in_sizes, int n_in,
                              void* d_out, int out_size, void* d_ws, size_t ws_size,
                              hipStream_t stream) {
    const float* logits    = (const float*)d_in[0];
    const float* features  = (const float*)d_in[1];
    const int*   edge      = (const int*)d_in[2];
    const float* Wf        = (const float*)d_in[3];
    const float* bfv       = (const float*)d_in[4];
    const float* deg_table = (const float*)d_in[5];
    const float* W1        = (const float*)d_in[6];
    const float* b1        = (const float*)d_in[7];
    const float* W2        = (const float*)d_in[8];
    const float* b2        = (const float*)d_in[9];
    const float* W3        = (const float*)d_in[10];
    const float* b3        = (const float*)d_in[11];
    float* out = (float*)d_out;

    // workspace carve-up (16B-aligned sections)
    int* rowptr    = (int*)d_ws;                 // N+1 (padded)
    int* adj       = rowptr + cN + 16;           // E
    int* desc      = adj + cE;                   // 128
    int* degidx    = desc + 128;                 // N
    float* dinv    = (float*)(degidx + cN);      // N
    float* bias2   = dinv + cN;                  // 128
    unsigned short* tb  = (unsigned short*)(bias2 + 128);          // N*128 bf16 (planar [4][N][32])
    unsigned short* hb  = tb + (size_t)cN * cHID;                  // N*128 bf16 (planar [4][N][32])
    unsigned short* Btc = hb + (size_t)cN * cHID;                  // 128*352
    unsigned short* Wt2 = Btc + 128 * cKF;                         // 128*128
    unsigned short* Wt3 = Wt2 + 128 * cHID;                        // 48*128
    unsigned* partial = (unsigned*)(Wt3 + 48 * cHID);              // 2*64*25000 u32

    // histograms + all weight preprocessing + desc init (one launch, 457 blocks)
    prep_kernel<<<457, 256, 0, stream>>>(edge, partial, Wf, bfv, W1, W2, W3,
                                         Btc, Wt2, Wt3, bias2, desc);

    // merged scan: chunk-prefix rewrite, rowptr, dinv, degidx (one launch, parallel lookback)
    mega_scan_kernel<<<cSCANB, 256, 0, stream>>>(partial, rowptr, dinv, degidx, desc);

    constexpr int MB = (cN + 63) / 64; // 782

    // merged: CSR scatter (128 blocks) + fused conv1 GEMM (782 blocks) -> tb planar
    scatter_gemm_kernel<<<128 + MB, 256, 0, stream>>>(edge, partial, rowptr, adj,
                                                      logits, features, deg_table, degidx,
                                                      Btc, bias2, dinv, tb);

    // agg1: one launch per channel group (3.2 MB plane L2-resident during each launch)
    for (int g = 0; g < 4; ++g)
        agg_cs<true><<<MB, 256, 0, stream>>>(tb, rowptr, adj, dinv, b1, hb, g);

    // conv2 (planar in/out)
    mfma_gemm<8, cHID, cHID, true><<<MB, 256, 0, stream>>>(hb, Wt2, dinv, tb);

    // agg2: per-group launches
    for (int g = 0; g < 4; ++g)
        agg_cs<true><<<MB, 256, 0, stream>>>(tb, rowptr, adj, dinv, b2, hb, g);

    // conv3 (planar in, flat [N][40] out)
    mfma_gemm<3, cNUM_CLASSES, cNUM_CLASSES, false><<<MB, 256, 0, stream>>>(hb, Wt3, dinv, tb);
    agg_bf40<<<(cN + 15) / 16, 128, 0, stream>>>(tb, rowptr, adj, dinv, b3, out);
}

// Round 12
// 275.526 us; speedup vs baseline: 1.1419x; 1.1049x over previous
//
#include <hip/hip_runtime.h>
#include <hip/hip_bf16.h>

// Problem constants (match reference)
constexpr int cN = 50000;
constexpr int cE = 800000;
constexpr int cNUM_CLASSES = 40;
constexpr int cFEAT_DIM = 256;
constexpr int cFEAT_HID = 64;
constexpr int cDEG_HID = 32;
constexpr int cHID = 128;
constexpr int cMAX_DEG = 256;
constexpr int cKF = 352;                // fused conv1 K: 40 logits + 256 feat + 32 deg + 24 pad
constexpr int cAST1 = 360;              // conv1 LDS A stride (pad +8)

// LDS-histogram CSR build parameters
constexpr int cNCHUNK = 64;             // edge chunks (= copies per histogram)
constexpr int cCHUNK  = cE / cNCHUNK;   // 12500 edges per chunk (exact)
constexpr int cWORDS  = cN / 2;         // 25000 packed u16-pair words per histogram
constexpr int cHWORDS = cWORDS / 2;     // 12500 words per node-range half (50 KB LDS)
constexpr int cSCANB  = (cWORDS + 255) / 256; // 98 blocks for mega_scan

typedef unsigned short ushort8_t __attribute__((ext_vector_type(8)));
typedef short short8_t __attribute__((ext_vector_type(8)));
typedef float float4_t __attribute__((ext_vector_type(4)));

__device__ __forceinline__ unsigned short f2bf(float f) {
    unsigned u = __builtin_bit_cast(unsigned, f);
    u += 0x7fff + ((u >> 16) & 1); // RNE
    return (unsigned short)(u >> 16);
}
__device__ __forceinline__ float bf2f(unsigned short s) {
    unsigned u = ((unsigned)s) << 16;
    return __builtin_bit_cast(float, u);
}

// ---------------- prep: histograms + all weight preprocessing + desc init ----------------
__global__ __launch_bounds__(256) void prep_kernel(const int* __restrict__ edge,
                                                   unsigned* __restrict__ partial,
                                                   const float* __restrict__ Wf,
                                                   const float* __restrict__ bfv,
                                                   const float* __restrict__ W1,
                                                   const float* __restrict__ W2,
                                                   const float* __restrict__ W3,
                                                   unsigned short* __restrict__ Btc,
                                                   unsigned short* __restrict__ Wt2,
                                                   unsigned short* __restrict__ Wt3,
                                                   float* __restrict__ bias2,
                                                   int* __restrict__ desc) {
    __shared__ unsigned lds[cHWORDS];
    const int b = blockIdx.x, tid = threadIdx.x;
    if (b < 256) {
        const int cb = b & (cNCHUNK - 1);
        const int half = (b >> 6) & 1;
        const int which = b >> 7;
        for (int i = tid; i < cHWORDS; i += 256) lds[i] = 0;
        __syncthreads();
        const int* ids = edge + (size_t)which * cE + (size_t)cb * cCHUNK;
        const int lo = half * (cN / 2), hi = lo + cN / 2;
        const int wbase = half * cHWORDS;
        for (int i = tid; i < cCHUNK; i += 256) {
            int v = ids[i];
            if (v >= lo && v < hi)
                atomicAdd(&lds[(v >> 1) - wbase], 1u << ((v & 1) * 16));
        }
        __syncthreads();
        unsigned* outp = partial + ((size_t)which * cNCHUNK + cb) * cWORDS + wbase;
        for (int i = tid; i < cHWORDS; i += 256) outp[i] = lds[i];
        return;
    }
    if (b < 392) {
        int i = (b - 256) * 256 + tid;
        if (i < 12288) {            // Btc: logits rows, deg rows, zero pad
            int n = i / 96, r = i - (i / 96) * 96;
            unsigned short v;
            if (r < 40)       v = f2bf(W1[r * cHID + n]);
            else if (r < 72)  v = f2bf(W1[(104 + r - 40) * cHID + n]);
            else              v = 0;
            int k = (r < 40) ? r : (r < 72 ? 296 + (r - 40) : 328 + (r - 72));
            Btc[n * cKF + k] = v;
            return;
        }
        i -= 12288;
        if (i < 16384) {            // Wt2
            int n = i >> 7, k = i & 127;
            Wt2[n * cHID + k] = f2bf(W2[k * cHID + n]);
            return;
        }
        i -= 16384;
        if (i < 6144) {             // Wt3 (48 x 128, n>=40 zero)
            int n = i >> 7, k = i & 127;
            Wt3[n * cHID + k] = (n < cNUM_CLASSES) ? f2bf(W3[k * cNUM_CLASSES + n]) : 0;
        }
        return;
    }
    if (b < 456) {                  // Wc[kf][n] = sum_j Wf[kf][j] * W1[40+j][n]
        int i = (b - 392) * 256 + tid;
        int kf = i >> 7, n = i & 127;
        float s = 0.f;
        #pragma unroll 8
        for (int j = 0; j < cFEAT_HID; ++j)
            s += Wf[kf * cFEAT_HID + j] * W1[(40 + j) * cHID + n];
        Btc[n * cKF + 40 + kf] = f2bf(s);
        return;
    }
    // bias2 + desc init
    if (tid < cHID) {
        float s = 0.f;
        #pragma unroll 8
        for (int j = 0; j < cFEAT_HID; ++j)
            s += bfv[j] * W1[(40 + j) * cHID + tid];
        bias2[tid] = s;
    } else if (tid - 128 < cSCANB) {
        desc[tid - 128] = 0;
    }
}

// ---------------- mega_scan: merge copies, chunk-prefix rewrite, rowptr, dinv, degidx ----------------
__global__ __launch_bounds__(256) void mega_scan_kernel(unsigned* __restrict__ partial,
                                                        int* __restrict__ rowptr,
                                                        float* __restrict__ dinv,
                                                        int* __restrict__ degidx,
                                                        int* __restrict__ desc) {
    const int b = blockIdx.x, tid = threadIdx.x;
    const int w = b * 256 + tid;
    unsigned slo = 0, shi = 0, plo = 0, phi = 0;
    if (w < cWORDS) {
        const unsigned* ps = partial + w;
        for (int c = 0; c < cNCHUNK; ++c) {
            unsigned v = ps[(size_t)c * cWORDS];
            slo += v & 0xFFFFu; shi += v >> 16;
        }
        unsigned* pd = partial + (size_t)cNCHUNK * cWORDS + w;
        for (int c = 0; c < cNCHUNK; ++c) {
            unsigned v = pd[(size_t)c * cWORDS];
            pd[(size_t)c * cWORDS] = plo | (phi << 16);   // per-chunk prefix (fits u16)
            plo += v & 0xFFFFu; phi += v >> 16;
        }
        int d0 = (int)(slo + plo), d1 = (int)(shi + phi);
        degidx[2 * w]     = d0 > cMAX_DEG - 1 ? cMAX_DEG - 1 : d0;
        degidx[2 * w + 1] = d1 > cMAX_DEG - 1 ? cMAX_DEG - 1 : d1;
    }
    __shared__ int s[256];
    int tot = (int)(plo + phi);
    s[tid] = tot;
    __syncthreads();
    #pragma unroll
    for (int off = 1; off < 256; off <<= 1) {
        int t = (tid >= off) ? s[tid - off] : 0;
        __syncthreads();
        s[tid] += t;
        __syncthreads();
    }
    int ex_local = s[tid] - tot;
    int block_total = s[255];
    if (tid == 0) atomicExch(&desc[b], block_total + 1);
    if (tid < b) {
        int v;
        do { v = atomicAdd(&desc[tid], 0); } while (v == 0);
        s[tid] = v - 1;
    }
    __syncthreads();
    if (tid >= b) s[tid] = 0;
    __syncthreads();
    #pragma unroll
    for (int off = 128; off > 0; off >>= 1) {
        if (tid < off) s[tid] += s[tid + off];
        __syncthreads();
    }
    int base = s[0] + ex_local;
    if (w < cWORDS) {
        rowptr[2 * w]     = base;
        rowptr[2 * w + 1] = base + (int)plo;
        dinv[2 * w]     = rsqrtf((float)(plo + 1));
        dinv[2 * w + 1] = rsqrtf((float)(phi + 1));
    }
    if (b == 0 && tid == 0) rowptr[cN] = cE;
}

// ---------------- merged: CSR scatter (blocks 0..127) + fused conv1 GEMM (blocks 128..909) ----------------
// GEMM role: bulk-stage 64x352 A-tile to LDS (one barrier), barrier-free MFMA loop.
// Epilogue: dinv-scaled, written PLANAR [4][N][32] (channel groups for agg layout).
__global__ __launch_bounds__(256) void scatter_gemm_kernel(const int* __restrict__ edge,
                                                           const unsigned* __restrict__ partial,
                                                           const int* __restrict__ rowptr,
                                                           int* __restrict__ adj,
                                                           const float* __restrict__ logits,
                                                           const float* __restrict__ features,
                                                           const float* __restrict__ deg_table,
                                                           const int* __restrict__ degidx,
                                                           const unsigned short* __restrict__ Btc,
                                                           const float* __restrict__ bias2,
                                                           const float* __restrict__ dinv,
                                                           unsigned short* __restrict__ out) {
    __shared__ unsigned shmem[cHWORDS];   // 50 KB, shared by both roles
    const int b = blockIdx.x, tid = threadIdx.x;

    if (b < 128) {
        // ---- scatter role (LDS prefix, no global atomics) ----
        const int cb = b & (cNCHUNK - 1);
        const int half = (b >> 6) & 1;
        const int wbase = half * cHWORDS;
        const unsigned* pp = partial + ((size_t)cNCHUNK + cb) * cWORDS + wbase;
        for (int i = tid; i < cHWORDS; i += 256) shmem[i] = pp[i];
        __syncthreads();
        const int* srcs = edge + (size_t)cb * cCHUNK;
        const int* dsts = edge + cE + (size_t)cb * cCHUNK;
        const int lo = half * (cN / 2), hi = lo + cN / 2;
        for (int i = tid; i < cCHUNK; i += 256) {
            int d = dsts[i];
            if (d >= lo && d < hi) {
                int sh = (d & 1) * 16;
                unsigned old = atomicAdd(&shmem[(d >> 1) - wbase], 1u << sh);
                int off = (int)((old >> sh) & 0xFFFFu);
                adj[rowptr[d] + off] = srcs[i];
            }
        }
        return;
    }

    // ---- fused conv1 GEMM role ----
    unsigned short* As = (unsigned short*)shmem;        // 64 x cAST1 = 46,080 B

    const int gb = b - 128;
    const int rowbase = gb * 64;
    const int arow = tid >> 2;
    const int akq = (tid & 3) * 8;
    int gr = rowbase + arow;
    if (gr > cN - 1) gr = cN - 1;
    const int didx = degidx[gr];

    // bulk staging: all 11 K-segments, issued back-to-back (22 float4 loads/thread)
    #pragma unroll
    for (int k0 = 0; k0 < cKF; k0 += 32) {
        #pragma unroll
        for (int h = 0; h < 2; ++h) {
            int k4 = k0 + akq + h * 4;
            float4 v = make_float4(0.f, 0.f, 0.f, 0.f);
            if (k4 < 40)       v = *(const float4*)&logits[(size_t)gr * cNUM_CLASSES + k4];
            else if (k4 < 296) v = *(const float4*)&features[(size_t)gr * cFEAT_DIM + (k4 - 40)];
            else if (k4 < 328) v = *(const float4*)&deg_table[didx * cDEG_HID + (k4 - 296)];
            unsigned long long p = (unsigned long long)f2bf(v.x)
                                 | ((unsigned long long)f2bf(v.y) << 16)
                                 | ((unsigned long long)f2bf(v.z) << 32)
                                 | ((unsigned long long)f2bf(v.w) << 48);
            *(unsigned long long*)&As[arow * cAST1 + k4] = p;
        }
    }
    __syncthreads();

    const int wave = tid >> 6;
    const int lane = tid & 63;
    const int m15 = lane & 15;
    const int q = lane >> 4;

    float4_t acc[4][2];
    #pragma unroll
    for (int mt = 0; mt < 4; ++mt)
        #pragma unroll
        for (int tt = 0; tt < 2; ++tt)
            acc[mt][tt] = (float4_t){0.f, 0.f, 0.f, 0.f};

    #pragma unroll
    for (int k0 = 0; k0 < cKF; k0 += 32) {
        short8_t bfr[2];
        #pragma unroll
        for (int tt = 0; tt < 2; ++tt)
            bfr[tt] = *(const short8_t*)&Btc[(size_t)((wave * 2 + tt) * 16 + m15) * cKF + k0 + q * 8];
        #pragma unroll
        for (int mt = 0; mt < 4; ++mt) {
            short8_t a = *(const short8_t*)&As[(mt * 16 + m15) * cAST1 + k0 + q * 8];
            acc[mt][0] = __builtin_amdgcn_mfma_f32_16x16x32_bf16(a, bfr[0], acc[mt][0], 0, 0, 0);
            acc[mt][1] = __builtin_amdgcn_mfma_f32_16x16x32_bf16(a, bfr[1], acc[mt][1], 0, 0, 0);
        }
    }

    #pragma unroll
    for (int mt = 0; mt < 4; ++mt) {
        #pragma unroll
        for (int r = 0; r < 4; ++r) {
            int row = rowbase + mt * 16 + q * 4 + r;
            if (row >= cN) continue;
            float dr = dinv[row];
            #pragma unroll
            for (int tt = 0; tt < 2; ++tt) {
                int col = (wave * 2 + tt) * 16 + m15;
                // planar [4][N][32]
                out[((size_t)(col >> 5) * cN + row) * 32 + (col & 31)] =
                    f2bf((acc[mt][tt][r] + bias2[col]) * dr);
            }
        }
    }
}

// ---------------- MFMA GEMM: planar A [4][N][32], optional planar out; dinv-scaled ----------------
template <int NT, int OSTR, int OUTC, bool POUT>
__global__ __launch_bounds__(256) void mfma_gemm(const unsigned short* __restrict__ A,
                                                 const unsigned short* __restrict__ Bt,
                                                 const float* __restrict__ dinv,
                                                 unsigned short* __restrict__ out) {
    constexpr int KTOT = 128;
    constexpr int AST = KTOT + 8;       // padded stride
    constexpr int KQ = KTOT / 8;        // 16 chunks of 8 ch
    __shared__ unsigned short As[64 * AST];
    __shared__ unsigned short Bs[NT * 16 * AST];

    const int tid = threadIdx.x;
    const int rowbase = blockIdx.x * 64;

    for (int i = tid; i < 64 * KQ; i += 256) {
        int r = i / KQ, c8 = i % KQ;
        int gr = rowbase + r;
        if (gr > cN - 1) gr = cN - 1;
        // planar source: plane c8>>2, offset (c8&3)*8
        *(ushort8_t*)&As[r * AST + c8 * 8] =
            *(const ushort8_t*)&A[((size_t)(c8 >> 2) * cN + gr) * 32 + (c8 & 3) * 8];
    }
    for (int i = tid; i < NT * 16 * KQ; i += 256) {
        int n = i / KQ, kq = (i % KQ) * 8;
        *(ushort8_t*)&Bs[n * AST + kq] = *(const ushort8_t*)&Bt[(size_t)n * KTOT + kq];
    }
    __syncthreads();

    const int wave = tid >> 6;
    const int lane = tid & 63;
    const int m15 = lane & 15;
    const int q = lane >> 4;

    float4_t acc[NT];
    #pragma unroll
    for (int t = 0; t < NT; ++t) acc[t] = (float4_t){0.f, 0.f, 0.f, 0.f};

    #pragma unroll
    for (int k0 = 0; k0 < KTOT; k0 += 32) {
        short8_t a = *(const short8_t*)&As[(wave * 16 + m15) * AST + k0 + q * 8];
        #pragma unroll
        for (int t = 0; t < NT; ++t) {
            short8_t b = *(const short8_t*)&Bs[(t * 16 + m15) * AST + k0 + q * 8];
            acc[t] = __builtin_amdgcn_mfma_f32_16x16x32_bf16(a, b, acc[t], 0, 0, 0);
        }
    }

    #pragma unroll
    for (int r = 0; r < 4; ++r) {
        int row = rowbase + wave * 16 + q * 4 + r;
        if (row >= cN) continue;
        float dr = dinv[row];
        #pragma unroll
        for (int t = 0; t < NT; ++t) {
            int col = t * 16 + m15;
            if (OUTC % 16 != 0 && col >= OUTC) continue;
            unsigned short v = f2bf(acc[t][r] * dr);
            if (POUT)
                out[((size_t)(col >> 5) * cN + row) * 32 + (col & 31)] = v;
            else
                out[(size_t)row * OSTR + col] = v;
        }
    }
}

// ---------------- channel-split GCN aggregate over planar t' [4][N][32] ----------------
template <bool RELU>
__global__ __launch_bounds__(256) void agg_cs(const unsigned short* __restrict__ t,
                                              const int* __restrict__ rowptr,
                                              const int* __restrict__ adj,
                                              const float* __restrict__ dinv,
                                              const float* __restrict__ bias,
                                              unsigned short* __restrict__ outb) {
    const int b = blockIdx.x, tid = threadIdx.x;
    const int g = b & 3;
    const int row = (b >> 2) * 64 + (tid >> 2);
    if (row >= cN) return;
    const int cl = (tid & 3) * 8;
    const float di = dinv[row];
    const unsigned short* tp = t + (size_t)g * cN * 32;
    int e = rowptr[row];
    const int end = rowptr[row + 1];
    float a0[8], a1[8], a2[8], a3[8];
    #pragma unroll
    for (int k = 0; k < 8; ++k) { a0[k] = 0.f; a1[k] = 0.f; a2[k] = 0.f; a3[k] = 0.f; }
    for (; e + 3 < end; e += 4) {
        int j0 = adj[e], j1 = adj[e + 1], j2 = adj[e + 2], j3 = adj[e + 3];
        ushort8_t t0 = *(const ushort8_t*)&tp[(size_t)j0 * 32 + cl];
        ushort8_t t1 = *(const ushort8_t*)&tp[(size_t)j1 * 32 + cl];
        ushort8_t t2 = *(const ushort8_t*)&tp[(size_t)j2 * 32 + cl];
        ushort8_t t3 = *(const ushort8_t*)&tp[(size_t)j3 * 32 + cl];
        #pragma unroll
        for (int k = 0; k < 8; ++k) {
            a0[k] += bf2f(t0[k]);
            a1[k] += bf2f(t1[k]);
            a2[k] += bf2f(t2[k]);
            a3[k] += bf2f(t3[k]);
        }
    }
    for (; e < end; ++e) {
        int j0 = adj[e];
        ushort8_t t0 = *(const ushort8_t*)&tp[(size_t)j0 * 32 + cl];
        #pragma unroll
        for (int k = 0; k < 8; ++k) a0[k] += bf2f(t0[k]);
    }
    ushort8_t ts = *(const ushort8_t*)&tp[(size_t)row * 32 + cl];
    ushort8_t o;
    #pragma unroll
    for (int k = 0; k < 8; ++k) {
        float r = di * (((a0[k] + a1[k]) + (a2[k] + a3[k])) + bf2f(ts[k])) + bias[g * 32 + cl + k];
        if (RELU) r = fmaxf(r, 0.f);
        o[k] = f2bf(r);
    }
    *(ushort8_t*)&outb[((size_t)g * cN + row) * 32 + cl] = o;
}

// ---------------- GCN aggregate over pre-scaled bf16 t' (40 ch, flat, final, fp32 out) ----------------
__global__ __launch_bounds__(128) void agg_bf40(const unsigned short* __restrict__ t,
                                                const int* __restrict__ rowptr,
                                                const int* __restrict__ adj,
                                                const float* __restrict__ dinv,
                                                const float* __restrict__ b,
                                                float* __restrict__ out) {
    const int tid = threadIdx.x;
    const int lane = tid & 7;
    const int row = blockIdx.x * 16 + (tid >> 3);
    if (row >= cN) return;
    const int c = lane * 8;
    if (c >= cNUM_CLASSES) return;
    const float di = dinv[row];
    int e = rowptr[row];
    const int end = rowptr[row + 1];
    float a0[8], a1[8], a2[8], a3[8];
    #pragma unroll
    for (int k = 0; k < 8; ++k) { a0[k] = 0.f; a1[k] = 0.f; a2[k] = 0.f; a3[k] = 0.f; }
    for (; e + 3 < end; e += 4) {
        int j0 = adj[e], j1 = adj[e + 1], j2 = adj[e + 2], j3 = adj[e + 3];
        ushort8_t t0 = *(const ushort8_t*)&t[(size_t)j0 * cNUM_CLASSES + c];
        ushort8_t t1 = *(const ushort8_t*)&t[(size_t)j1 * cNUM_CLASSES + c];
        ushort8_t t2 = *(const ushort8_t*)&t[(size_t)j2 * cNUM_CLASSES + c];
        ushort8_t t3 = *(const ushort8_t*)&t[(size_t)j3 * cNUM_CLASSES + c];
        #pragma unroll
        for (int k = 0; k < 8; ++k) {
            a0[k] += bf2f(t0[k]);
            a1[k] += bf2f(t1[k]);
            a2[k] += bf2f(t2[k]);
            a3[k] += bf2f(t3[k]);
        }
    }
    for (; e < end; ++e) {
        int j0 = adj[e];
        ushort8_t t0 = *(const ushort8_t*)&t[(size_t)j0 * cNUM_CLASSES + c];
        #pragma unroll
        for (int k = 0; k < 8; ++k) a0[k] += bf2f(t0[k]);
    }
    ushort8_t ts = *(const ushort8_t*)&t[(size_t)row * cNUM_CLASSES + c];
    float r[8];
    #pragma unroll
    for (int k = 0; k < 8; ++k)
        r[k] = di * (((a0[k] + a1[k]) + (a2[k] + a3[k])) + bf2f(ts[k])) + b[c + k];
    float4 v0 = make_float4(r[0], r[1], r[2], r[3]);
    float4 v1 = make_float4(r[4], r[5], r[6], r[7]);
    *(float4*)&out[(size_t)row * cNUM_CLASSES + c] = v0;
    *(float4*)&out[(size_t)row * cNUM_CLASSES + c + 4] = v1;
}

extern "C" void kernel_launch(void* const* d_in, const int* in_sizes, int n_in,
                              void* d_out, int out_size, void* d_ws, size_t ws_size,
                              hipStream_t stream) {
    const float* logits    = (const float*)d_in[0];
    const float* features  = (const float*)d_in[1];
    const int*   edge      = (const int*)d_in[2];
    const float* Wf        = (const float*)d_in[3];
    const float* bfv       = (const float*)d_in[4];
    const float* deg_table = (const float*)d_in[5];
    const float* W1        = (const float*)d_in[6];
    const float* b1        = (const float*)d_in[7];
    const float* W2        = (const float*)d_in[8];
    const float* b2        = (const float*)d_in[9];
    const float* W3        = (const float*)d_in[10];
    const float* b3        = (const float*)d_in[11];
    float* out = (float*)d_out;

    // workspace carve-up (16B-aligned sections)
    int* rowptr    = (int*)d_ws;                 // N+1 (padded)
    int* adj       = rowptr + cN + 16;           // E
    int* desc      = adj + cE;                   // 128
    int* degidx    = desc + 128;                 // N
    float* dinv    = (float*)(degidx + cN);      // N
    float* bias2   = dinv + cN;                  // 128
    unsigned short* tb  = (unsigned short*)(bias2 + 128);          // N*128 bf16 (planar [4][N][32])
    unsigned short* hb  = tb + (size_t)cN * cHID;                  // N*128 bf16 (planar [4][N][32])
    unsigned short* Btc = hb + (size_t)cN * cHID;                  // 128*352
    unsigned short* Wt2 = Btc + 128 * cKF;                         // 128*128
    unsigned short* Wt3 = Wt2 + 128 * cHID;                        // 48*128
    unsigned* partial = (unsigned*)(Wt3 + 48 * cHID);              // 2*64*25000 u32

    // histograms + all weight preprocessing + desc init (one launch, 457 blocks)
    prep_kernel<<<457, 256, 0, stream>>>(edge, partial, Wf, bfv, W1, W2, W3,
                                         Btc, Wt2, Wt3, bias2, desc);

    // merged scan: chunk-prefix rewrite, rowptr, dinv, degidx (one launch, parallel lookback)
    mega_scan_kernel<<<cSCANB, 256, 0, stream>>>(partial, rowptr, dinv, degidx, desc);

    constexpr int MB = (cN + 63) / 64; // 782
    constexpr int AGB = MB * 4;        // 3128 channel-split agg blocks

    // merged: CSR scatter (128 blocks) + fused conv1 GEMM (782 blocks)
    scatter_gemm_kernel<<<128 + MB, 256, 0, stream>>>(edge, partial, rowptr, adj,
                                                      logits, features, deg_table, degidx,
                                                      Btc, bias2, dinv, tb);
    agg_cs<true><<<AGB, 256, 0, stream>>>(tb, rowptr, adj, dinv, b1, hb);

    // conv2
    mfma_gemm<8, cHID, cHID, true><<<MB, 256, 0, stream>>>(hb, Wt2, dinv, tb);
    agg_cs<true><<<AGB, 256, 0, stream>>>(tb, rowptr, adj, dinv, b2, hb);

    // conv3 (flat [N][40] out)
    mfma_gemm<3, cNUM_CLASSES, cNUM_CLASSES, false><<<MB, 256, 0, stream>>>(hb, Wt3, dinv, tb);
    agg_bf40<<<(cN + 15) / 16, 128, 0, stream>>>(tb, rowptr, adj, dinv, b3, out);
}